// Round 4
// baseline (313.378 us; speedup 1.0000x reference)
//
#include <hip/hip_runtime.h>

// MatrixFactorization: out[i] = dot(user_i, item_table[dest_i])
// user_i = b + sum_k emb_k[idx_k[i]] @ W_k  (W_k = rows [4k,4k+4) of W[24,32])
// Round 4: 1 row/thread + DISTRIBUTIVE dot (each LDS quad consumed immediately,
// no 6-quad sum temporaries) -> live set ~30 regs. __launch_bounds__(256,6):
// VGPR cap ~85 (no spill), 6 blocks/CU = LDS limit (6 x 25,344 B).

#define NF 32
#define LDS_STRIDE 36           // floats per padded table row (144 B, 16B-aligned)
#define NV 176                  // 7+24+2+100+12+31 vocab entries

__device__ __forceinline__ float4 ldsf4(const float* p) {
    return *reinterpret_cast<const float4*>(p);
}

__device__ __forceinline__ float dot4(float4 u, float4 v, float a) {
    a = fmaf(u.x, v.x, a);
    a = fmaf(u.y, v.y, a);
    a = fmaf(u.z, v.z, a);
    a = fmaf(u.w, v.w, a);
    return a;
}

__global__ __launch_bounds__(256, 6)
void mf_kernel(const int* __restrict__ dow, const int* __restrict__ tmi,
               const int* __restrict__ sx,  const int* __restrict__ ag,
               const int* __restrict__ mo,  const int* __restrict__ dy,
               const int* __restrict__ dst,
               const float* __restrict__ e_dow,   const float* __restrict__ e_time,
               const float* __restrict__ e_sex,   const float* __restrict__ e_age,
               const float* __restrict__ e_month, const float* __restrict__ e_day,
               const float* __restrict__ W, const float* __restrict__ bvec,
               const float* __restrict__ item_table,
               float* __restrict__ out, int n)
{
    __shared__ float proj[NV * LDS_STRIDE];   // 25,344 B

    // ---- Stage 1: build projected vocab tables in LDS ----
    // entry ranges: dow [0,7) time [7,31) sex [31,33) age [33,133) month [133,145) day [145,176)
    const int tid = threadIdx.x;
    for (int t = tid; t < NV * NF; t += blockDim.x) {
        int entry = t >> 5;
        int f     = t & 31;
        int k, v;
        const float* e;
        if      (entry < 7)   { k = 0; v = entry;       e = e_dow;   }
        else if (entry < 31)  { k = 1; v = entry - 7;   e = e_time;  }
        else if (entry < 33)  { k = 2; v = entry - 31;  e = e_sex;   }
        else if (entry < 133) { k = 3; v = entry - 33;  e = e_age;   }
        else if (entry < 145) { k = 4; v = entry - 133; e = e_month; }
        else                  { k = 5; v = entry - 145; e = e_day;   }
        float acc = (k == 0) ? bvec[f] : 0.0f;
        #pragma unroll
        for (int d = 0; d < 4; ++d)
            acc += e[v * 4 + d] * W[(k * 4 + d) * NF + f];
        proj[entry * LDS_STRIDE + f] = acc;
    }
    __syncthreads();

    // ---- Stage 2: 1 row per thread, grid-stride (4 trips at N=2M) ----
    const int tstride = gridDim.x * blockDim.x;
    for (int i = blockIdx.x * blockDim.x + tid; i < n; i += tstride) {
        const int b0 = (0   + dow[i]) * LDS_STRIDE;
        const int b1 = (7   + tmi[i]) * LDS_STRIDE;
        const int b2 = (31  + sx[i])  * LDS_STRIDE;
        const int b3 = (33  + ag[i])  * LDS_STRIDE;
        const int b4 = (133 + mo[i])  * LDS_STRIDE;
        const int b5 = (145 + dy[i])  * LDS_STRIDE;
        const float4* it = reinterpret_cast<const float4*>(item_table + (long long)dst[i] * NF);

        float acc0 = 0.0f, acc1 = 0.0f, acc2 = 0.0f;
        #pragma unroll
        for (int q = 0; q < 8; ++q) {
            float4 iv = it[q];
            acc0 = dot4(ldsf4(&proj[b0 + q * 4]), iv, acc0);
            acc1 = dot4(ldsf4(&proj[b1 + q * 4]), iv, acc1);
            acc2 = dot4(ldsf4(&proj[b2 + q * 4]), iv, acc2);
            acc0 = dot4(ldsf4(&proj[b3 + q * 4]), iv, acc0);
            acc1 = dot4(ldsf4(&proj[b4 + q * 4]), iv, acc1);
            acc2 = dot4(ldsf4(&proj[b5 + q * 4]), iv, acc2);
        }
        out[i] = acc0 + acc1 + acc2;
    }
}

extern "C" void kernel_launch(void* const* d_in, const int* in_sizes, int n_in,
                              void* d_out, int out_size, void* d_ws, size_t ws_size,
                              hipStream_t stream) {
    const int* dow = (const int*)d_in[0];
    const int* tmi = (const int*)d_in[1];
    const int* sx  = (const int*)d_in[2];
    const int* ag  = (const int*)d_in[3];
    const int* mo  = (const int*)d_in[4];
    const int* dy  = (const int*)d_in[5];
    const int* dst = (const int*)d_in[6];
    const float* e_dow   = (const float*)d_in[7];
    const float* e_time  = (const float*)d_in[8];
    const float* e_sex   = (const float*)d_in[9];
    const float* e_age   = (const float*)d_in[10];
    const float* e_month = (const float*)d_in[11];
    const float* e_day   = (const float*)d_in[12];
    const float* W       = (const float*)d_in[13];
    const float* bvec    = (const float*)d_in[14];
    const float* item    = (const float*)d_in[15];
    float* out = (float*)d_out;
    const int n = in_sizes[0];

    dim3 grid(2048), block(256);
    mf_kernel<<<grid, block, 0, stream>>>(dow, tmi, sx, ag, mo, dy, dst,
                                          e_dow, e_time, e_sex, e_age, e_month, e_day,
                                          W, bvec, item, out, n);
}

// Round 5
// 234.871 us; speedup vs baseline: 1.3343x; 1.3343x over previous
//
#include <hip/hip_runtime.h>

// MatrixFactorization: out[i] = dot(user_i, item_table[dest_i])
// user_i = b + sum_k emb_k[idx_k[i]] @ W_k  (W_k = rows [4k,4k+4) of W[24,32])
// Round 5: item row (128 B = exactly one L2 line) loaded as 8 back-to-back
// float4s into NAMED registers -> single temporally-atomic line visit
// (round 4 spread the 8 touches ~800 cy apart and thrashed L2: 622 MB fetch).
// Index streams + output use nontemporal hints so 67 MB of streaming traffic
// doesn't evict the 12.8 MB item table from L2.

#define NF 32
#define LDS_STRIDE 36           // floats per padded table row (144 B, 16B-aligned)
#define NV 176                  // 7+24+2+100+12+31 vocab entries

__device__ __forceinline__ float4 ldsf4(const float* p) {
    return *reinterpret_cast<const float4*>(p);
}

__device__ __forceinline__ float dot4(float4 u, float4 v, float a) {
    a = fmaf(u.x, v.x, a);
    a = fmaf(u.y, v.y, a);
    a = fmaf(u.z, v.z, a);
    a = fmaf(u.w, v.w, a);
    return a;
}

// one item quad (IV, quad index Q) against all 6 user tables, 3 acc chains
#define QUAD(IV, Q)                                                  \
    acc0 = dot4(ldsf4(&proj[b0 + (Q) * 4]), IV, acc0);               \
    acc1 = dot4(ldsf4(&proj[b1 + (Q) * 4]), IV, acc1);               \
    acc2 = dot4(ldsf4(&proj[b2 + (Q) * 4]), IV, acc2);               \
    acc0 = dot4(ldsf4(&proj[b3 + (Q) * 4]), IV, acc0);               \
    acc1 = dot4(ldsf4(&proj[b4 + (Q) * 4]), IV, acc1);               \
    acc2 = dot4(ldsf4(&proj[b5 + (Q) * 4]), IV, acc2);

__global__ __launch_bounds__(256, 6)
void mf_kernel(const int* __restrict__ dow, const int* __restrict__ tmi,
               const int* __restrict__ sx,  const int* __restrict__ ag,
               const int* __restrict__ mo,  const int* __restrict__ dy,
               const int* __restrict__ dst,
               const float* __restrict__ e_dow,   const float* __restrict__ e_time,
               const float* __restrict__ e_sex,   const float* __restrict__ e_age,
               const float* __restrict__ e_month, const float* __restrict__ e_day,
               const float* __restrict__ W, const float* __restrict__ bvec,
               const float* __restrict__ item_table,
               float* __restrict__ out, int n)
{
    __shared__ float proj[NV * LDS_STRIDE];   // 25,344 B

    // ---- Stage 1: build projected vocab tables in LDS ----
    // entry ranges: dow [0,7) time [7,31) sex [31,33) age [33,133) month [133,145) day [145,176)
    const int tid = threadIdx.x;
    for (int t = tid; t < NV * NF; t += blockDim.x) {
        int entry = t >> 5;
        int f     = t & 31;
        int k, v;
        const float* e;
        if      (entry < 7)   { k = 0; v = entry;       e = e_dow;   }
        else if (entry < 31)  { k = 1; v = entry - 7;   e = e_time;  }
        else if (entry < 33)  { k = 2; v = entry - 31;  e = e_sex;   }
        else if (entry < 133) { k = 3; v = entry - 33;  e = e_age;   }
        else if (entry < 145) { k = 4; v = entry - 133; e = e_month; }
        else                  { k = 5; v = entry - 145; e = e_day;   }
        float acc = (k == 0) ? bvec[f] : 0.0f;
        #pragma unroll
        for (int d = 0; d < 4; ++d)
            acc += e[v * 4 + d] * W[(k * 4 + d) * NF + f];
        proj[entry * LDS_STRIDE + f] = acc;
    }
    __syncthreads();

    // ---- Stage 2: 1 row per thread, grid-stride ----
    const int tstride = gridDim.x * blockDim.x;
    for (int i = blockIdx.x * blockDim.x + tid; i < n; i += tstride) {
        const int b0 = (0   + __builtin_nontemporal_load(&dow[i])) * LDS_STRIDE;
        const int b1 = (7   + __builtin_nontemporal_load(&tmi[i])) * LDS_STRIDE;
        const int b2 = (31  + __builtin_nontemporal_load(&sx[i]))  * LDS_STRIDE;
        const int b3 = (33  + __builtin_nontemporal_load(&ag[i]))  * LDS_STRIDE;
        const int b4 = (133 + __builtin_nontemporal_load(&mo[i]))  * LDS_STRIDE;
        const int b5 = (145 + __builtin_nontemporal_load(&dy[i]))  * LDS_STRIDE;
        const int   d = __builtin_nontemporal_load(&dst[i]);
        const float4* it = reinterpret_cast<const float4*>(item_table + (long long)d * NF);

        // whole 128 B row (one L2 line) in one temporally-atomic burst
        const float4 iv0 = it[0];
        const float4 iv1 = it[1];
        const float4 iv2 = it[2];
        const float4 iv3 = it[3];
        const float4 iv4 = it[4];
        const float4 iv5 = it[5];
        const float4 iv6 = it[6];
        const float4 iv7 = it[7];

        float acc0 = 0.0f, acc1 = 0.0f, acc2 = 0.0f;
        QUAD(iv0, 0)
        QUAD(iv1, 1)
        QUAD(iv2, 2)
        QUAD(iv3, 3)
        QUAD(iv4, 4)
        QUAD(iv5, 5)
        QUAD(iv6, 6)
        QUAD(iv7, 7)
        __builtin_nontemporal_store(acc0 + acc1 + acc2, &out[i]);
    }
}

extern "C" void kernel_launch(void* const* d_in, const int* in_sizes, int n_in,
                              void* d_out, int out_size, void* d_ws, size_t ws_size,
                              hipStream_t stream) {
    const int* dow = (const int*)d_in[0];
    const int* tmi = (const int*)d_in[1];
    const int* sx  = (const int*)d_in[2];
    const int* ag  = (const int*)d_in[3];
    const int* mo  = (const int*)d_in[4];
    const int* dy  = (const int*)d_in[5];
    const int* dst = (const int*)d_in[6];
    const float* e_dow   = (const float*)d_in[7];
    const float* e_time  = (const float*)d_in[8];
    const float* e_sex   = (const float*)d_in[9];
    const float* e_age   = (const float*)d_in[10];
    const float* e_month = (const float*)d_in[11];
    const float* e_day   = (const float*)d_in[12];
    const float* W       = (const float*)d_in[13];
    const float* bvec    = (const float*)d_in[14];
    const float* item    = (const float*)d_in[15];
    float* out = (float*)d_out;
    const int n = in_sizes[0];

    dim3 grid(2048), block(256);
    mf_kernel<<<grid, block, 0, stream>>>(dow, tmi, sx, ag, mo, dy, dst,
                                          e_dow, e_time, e_sex, e_age, e_month, e_day,
                                          W, bvec, item, out, n);
}

// Round 6
// 171.551 us; speedup vs baseline: 1.8267x; 1.3691x over previous
//
#include <hip/hip_runtime.h>

// MatrixFactorization: out[i] = dot(user_i, item_table[dest_i])
// user_i = b + sum_k emb_k[idx_k[i]] @ W_k  (W_k = rows [4k,4k+4) of W[24,32])
// Round 6: round 5's VGPR=40 allocation serialized the 8 item-quad loads
// (32 regs of payload can't fit a 40-reg budget) -> each row paid ~8 serial
// L2/HBM latencies. Fix: __launch_bounds__(256,4) (128-reg budget) + a
// compiler memory fence after issuing ALL loads (8 item quads + next trip's
// 7 indices) so they stay batched under one s_waitcnt, + manual 2-deep
// index pipeline across grid-stride trips.

#define NF 32
#define LDS_STRIDE 36           // floats per padded table row (144 B, 16B-aligned)
#define NV 176                  // 7+24+2+100+12+31 vocab entries

__device__ __forceinline__ float4 ldsf4(const float* p) {
    return *reinterpret_cast<const float4*>(p);
}

__device__ __forceinline__ float dot4(float4 u, float4 v, float a) {
    a = fmaf(u.x, v.x, a);
    a = fmaf(u.y, v.y, a);
    a = fmaf(u.z, v.z, a);
    a = fmaf(u.w, v.w, a);
    return a;
}

// one item quad (IV, quad index Q) against all 6 user tables, 3 acc chains
#define QUAD(IV, Q)                                                  \
    acc0 = dot4(ldsf4(&proj[b0 + (Q) * 4]), IV, acc0);               \
    acc1 = dot4(ldsf4(&proj[b1 + (Q) * 4]), IV, acc1);               \
    acc2 = dot4(ldsf4(&proj[b2 + (Q) * 4]), IV, acc2);               \
    acc0 = dot4(ldsf4(&proj[b3 + (Q) * 4]), IV, acc0);               \
    acc1 = dot4(ldsf4(&proj[b4 + (Q) * 4]), IV, acc1);               \
    acc2 = dot4(ldsf4(&proj[b5 + (Q) * 4]), IV, acc2);

#define NTL(P) __builtin_nontemporal_load(P)

__global__ __launch_bounds__(256, 4)
void mf_kernel(const int* __restrict__ dow, const int* __restrict__ tmi,
               const int* __restrict__ sx,  const int* __restrict__ ag,
               const int* __restrict__ mo,  const int* __restrict__ dy,
               const int* __restrict__ dst,
               const float* __restrict__ e_dow,   const float* __restrict__ e_time,
               const float* __restrict__ e_sex,   const float* __restrict__ e_age,
               const float* __restrict__ e_month, const float* __restrict__ e_day,
               const float* __restrict__ W, const float* __restrict__ bvec,
               const float* __restrict__ item_table,
               float* __restrict__ out, int n)
{
    __shared__ float proj[NV * LDS_STRIDE];   // 25,344 B

    // ---- Stage 1: build projected vocab tables in LDS ----
    // entry ranges: dow [0,7) time [7,31) sex [31,33) age [33,133) month [133,145) day [145,176)
    const int tid = threadIdx.x;
    for (int t = tid; t < NV * NF; t += blockDim.x) {
        int entry = t >> 5;
        int f     = t & 31;
        int k, v;
        const float* e;
        if      (entry < 7)   { k = 0; v = entry;       e = e_dow;   }
        else if (entry < 31)  { k = 1; v = entry - 7;   e = e_time;  }
        else if (entry < 33)  { k = 2; v = entry - 31;  e = e_sex;   }
        else if (entry < 133) { k = 3; v = entry - 33;  e = e_age;   }
        else if (entry < 145) { k = 4; v = entry - 133; e = e_month; }
        else                  { k = 5; v = entry - 145; e = e_day;   }
        float acc = (k == 0) ? bvec[f] : 0.0f;
        #pragma unroll
        for (int d = 0; d < 4; ++d)
            acc += e[v * 4 + d] * W[(k * 4 + d) * NF + f];
        proj[entry * LDS_STRIDE + f] = acc;
    }
    __syncthreads();

    // ---- Stage 2: 1 row/thread, grid-stride, 2-deep index pipeline ----
    const int tstride = gridDim.x * blockDim.x;
    int i = blockIdx.x * blockDim.x + tid;
    if (i >= n) return;

    // prologue: indices for first trip
    int j0 = NTL(&dow[i]), j1 = NTL(&tmi[i]), j2 = NTL(&sx[i]),
        j3 = NTL(&ag[i]),  j4 = NTL(&mo[i]),  j5 = NTL(&dy[i]),
        jd = NTL(&dst[i]);

    for (;;) {
        const int b0 = (0   + j0) * LDS_STRIDE;
        const int b1 = (7   + j1) * LDS_STRIDE;
        const int b2 = (31  + j2) * LDS_STRIDE;
        const int b3 = (33  + j3) * LDS_STRIDE;
        const int b4 = (133 + j4) * LDS_STRIDE;
        const int b5 = (145 + j5) * LDS_STRIDE;
        const float4* it = reinterpret_cast<const float4*>(item_table + (long long)jd * NF);

        // whole 128 B row (one L2 line) in one burst
        float4 iv0 = it[0];
        float4 iv1 = it[1];
        float4 iv2 = it[2];
        float4 iv3 = it[3];
        float4 iv4 = it[4];
        float4 iv5 = it[5];
        float4 iv6 = it[6];
        float4 iv7 = it[7];

        // prefetch next trip's indices while the item row is in flight
        const int ni = i + tstride;
        const bool more = ni < n;          // wave-uniform (n, stride multiples of 64)
        if (more) {
            j0 = NTL(&dow[ni]); j1 = NTL(&tmi[ni]); j2 = NTL(&sx[ni]);
            j3 = NTL(&ag[ni]);  j4 = NTL(&mo[ni]);  j5 = NTL(&dy[ni]);
            jd = NTL(&dst[ni]);
        }

        // fence: no load may be sunk below this point -> one batched vmcnt wait
        asm volatile("" ::: "memory");

        float acc0 = 0.0f, acc1 = 0.0f, acc2 = 0.0f;
        QUAD(iv0, 0)
        QUAD(iv1, 1)
        QUAD(iv2, 2)
        QUAD(iv3, 3)
        QUAD(iv4, 4)
        QUAD(iv5, 5)
        QUAD(iv6, 6)
        QUAD(iv7, 7)
        __builtin_nontemporal_store(acc0 + acc1 + acc2, &out[i]);

        if (!more) break;
        i = ni;
    }
}

extern "C" void kernel_launch(void* const* d_in, const int* in_sizes, int n_in,
                              void* d_out, int out_size, void* d_ws, size_t ws_size,
                              hipStream_t stream) {
    const int* dow = (const int*)d_in[0];
    const int* tmi = (const int*)d_in[1];
    const int* sx  = (const int*)d_in[2];
    const int* ag  = (const int*)d_in[3];
    const int* mo  = (const int*)d_in[4];
    const int* dy  = (const int*)d_in[5];
    const int* dst = (const int*)d_in[6];
    const float* e_dow   = (const float*)d_in[7];
    const float* e_time  = (const float*)d_in[8];
    const float* e_sex   = (const float*)d_in[9];
    const float* e_age   = (const float*)d_in[10];
    const float* e_month = (const float*)d_in[11];
    const float* e_day   = (const float*)d_in[12];
    const float* W       = (const float*)d_in[13];
    const float* bvec    = (const float*)d_in[14];
    const float* item    = (const float*)d_in[15];
    float* out = (float*)d_out;
    const int n = in_sizes[0];

    dim3 grid(2048), block(256);
    mf_kernel<<<grid, block, 0, stream>>>(dow, tmi, sx, ag, mo, dy, dst,
                                          e_dow, e_time, e_sex, e_age, e_month, e_day,
                                          W, bvec, item, out, n);
}